// Round 3
// baseline (73.698 us; speedup 1.0000x reference)
//
#include <hip/hip_runtime.h>
#include <math.h>
#include <stdint.h>

#define RR 1000
#define CC 1024
#define NCLS 81
#define HH 1024.0f
#define MIN_CONF_V 0.05f
#define NMS_THR_V 0.5f
#define NEGV -1e9f

// ---------------- Kernel 0: repack weights -> wP[12][256][32] ----------------
// wP[g][kstep][ci*4 + kk] = w[:, g*8+ci] at k = kstep*4+kk   (96 padded cols)
__global__ __launch_bounds__(128) void k0_wt(
    const float* __restrict__ w_cls, const float* __restrict__ w_delta,
    float* __restrict__ wP)
{
    const int t = threadIdx.x;
    if (t >= 96) return;
    const int c = t;
    const int g = c >> 3, ci = c & 7;
    #pragma unroll
    for (int kk = 0; kk < 4; ++kk) {
        const int k = blockIdx.x * 4 + kk;
        float v = 0.f;
        if (c < NCLS)            v = w_cls[(size_t)k * NCLS + c];
        else if (c < NCLS + 4)   v = w_delta[(size_t)k * 4 + (c - NCLS)];
        wP[(size_t)g * 8192 + (size_t)(k >> 2) * 32 + ci * 4 + (k & 3)] = v;
    }
}

// ---------------- Kernel 1: split-K f32 GEMM, w scalar-loaded ----------------
// grid 250 = 125 row-tiles x 2 K-halves. 768 thr = 12 waves.
// wave wq: 64 rows (lane=row) x 8 cols (g=wq). x in LDS (XOR swizzle), w in SGPRs.
__global__ __launch_bounds__(768) void k1_gemm(
    const float* __restrict__ x, const float* __restrict__ wP,
    float* __restrict__ partial)
{
    __shared__ float4 xs4[2][1024];           // [buf][row*16 + swz f4], 32 KB

    const int t = threadIdx.x;
    const int bx = blockIdx.x;
    const int rt = bx >> 1;                   // 0..124
    const int kh = bx & 1;                    // K half
    const int row0 = rt * 64;
    const int kbase = kh * 512;
    const int lane = t & 63;                  // = row within tile
    const int wq = __builtin_amdgcn_readfirstlane(t >> 6);  // 0..11, wave-uniform

    // staging: 1024 float4 per chunk; thread t does idx t, and t+768 if t<256
    const int r_s0 = t >> 4;                  // 0..47
    const int f_s0 = t & 15;
    const int dst0 = (r_s0 << 4) + (f_s0 ^ (r_s0 & 15));
    const size_t gsrc0 = (size_t)(row0 + r_s0) * CC + kbase + f_s0 * 4;
    const int r_s1 = 48 + (t >> 4);           // valid only t<256 -> rows 48..63
    const int f_s1 = t & 15;
    const int dst1 = (r_s1 << 4) + (f_s1 ^ (r_s1 & 15));
    const size_t gsrc1 = (size_t)(row0 + r_s1) * CC + kbase + f_s1 * 4;

    float acc[8] = {0.f, 0.f, 0.f, 0.f, 0.f, 0.f, 0.f, 0.f};

    float4 pv0 = *(const float4*)(x + gsrc0);
    float4 pv1;
    if (t < 256) pv1 = *(const float4*)(x + gsrc1);

    int cur = 0;
    for (int ch = 0; ch < 8; ++ch) {
        xs4[cur][dst0] = pv0;
        if (t < 256) xs4[cur][dst1] = pv1;
        __syncthreads();
        if (ch < 7) {
            const size_t off = (size_t)(ch + 1) * 64;
            pv0 = *(const float4*)(x + gsrc0 + off);
            if (t < 256) pv1 = *(const float4*)(x + gsrc1 + off);
        }
        // wave-uniform w fragment base for this chunk (16 steps x 32 floats)
        const float* __restrict__ wb = wP + ((size_t)wq << 13)
                                     + (size_t)(kh * 128 + ch * 16) * 32;
        float wA[32], wB[32];
        #pragma unroll
        for (int i = 0; i < 32; ++i) wA[i] = wb[i];
        const float4* xsb = xs4[cur];
        #pragma unroll
        for (int s = 0; s < 16; ++s) {
            float* wc = ((s & 1) == 0) ? wA : wB;
            float* wn = ((s & 1) == 0) ? wB : wA;
            if (s < 15) {
                #pragma unroll
                for (int i = 0; i < 32; ++i) wn[i] = wb[(s + 1) * 32 + i];
            }
            const float4 xv = xsb[(lane << 4) + (s ^ (lane & 15))];
            #pragma unroll
            for (int j = 0; j < 8; ++j) {
                acc[j] = fmaf(xv.x, wc[j * 4 + 0], acc[j]);
                acc[j] = fmaf(xv.y, wc[j * 4 + 1], acc[j]);
                acc[j] = fmaf(xv.z, wc[j * 4 + 2], acc[j]);
                acc[j] = fmaf(xv.w, wc[j * 4 + 3], acc[j]);
            }
        }
        __syncthreads();
        cur ^= 1;
    }

    float* po = partial + ((size_t)(kh * 8000 + row0 + lane)) * 96 + (t >> 6) * 8;
    *(float4*)(po + 0) = make_float4(acc[0], acc[1], acc[2], acc[3]);
    *(float4*)(po + 4) = make_float4(acc[4], acc[5], acc[6], acc[7]);
}

// ---------------- Kernel 1b: reduce halves + softmax/argmax + bbox ----------------
// grid 125 x 1024 thr: 64 rows/block, 16 threads per row.
__global__ __launch_bounds__(1024) void k1b_epi(
    const float* __restrict__ partial, const float* __restrict__ b_cls,
    const float* __restrict__ b_delta, const float* __restrict__ rois,
    float* __restrict__ bx_ws, float* __restrict__ sc_ws, float* __restrict__ cid_ws)
{
    const int t = threadIdx.x;
    const int rb = t >> 4;
    const int e = t & 15;
    const int gr = blockIdx.x * 64 + rb;
    const float* pa = partial + (size_t)gr * 96;
    const float* pb = partial + (size_t)(8000 + gr) * 96;

    float v[6];
    float vmax = -INFINITY;
    int imax = 1 << 20;
    #pragma unroll
    for (int s = 0; s < 6; ++s) {
        const int c = e + 16 * s;
        if (c < NCLS) {
            const float val = pa[c] + pb[c] + b_cls[c];
            v[s] = val;
            if (val > vmax) { vmax = val; imax = c; }
        } else v[s] = -INFINITY;
    }
    #pragma unroll
    for (int m = 8; m >= 1; m >>= 1) {
        const float v2 = __shfl_xor(vmax, m);
        const int   i2 = __shfl_xor(imax, m);
        if (v2 > vmax || (v2 == vmax && i2 < imax)) { vmax = v2; imax = i2; }
    }
    float sume = 0.f;
    #pragma unroll
    for (int s = 0; s < 6; ++s) {
        const int c = e + 16 * s;
        if (c < NCLS) sume += expf(v[s] - vmax);
    }
    #pragma unroll
    for (int m = 8; m >= 1; m >>= 1) sume += __shfl_xor(sume, m);

    if (e == 0) {
        const float score = 1.0f / sume;
        const int cid = imax;
        const float d0 = (pa[81] + pb[81] + b_delta[0]) * 0.1f;
        const float d1 = (pa[82] + pb[82] + b_delta[1]) * 0.1f;
        const float d2 = (pa[83] + pb[83] + b_delta[2]) * 0.2f;
        const float d3 = (pa[84] + pb[84] + b_delta[3]) * 0.2f;
        const float y1 = rois[(size_t)gr * 5 + 1] * HH;
        const float x1 = rois[(size_t)gr * 5 + 2] * HH;
        const float y2 = rois[(size_t)gr * 5 + 3] * HH;
        const float x2 = rois[(size_t)gr * 5 + 4] * HH;
        const float h = y2 - y1, w = x2 - x1;
        const float cy = y1 + 0.5f * h + d0 * h;
        const float cx = x1 + 0.5f * w + d1 * w;
        const float h2 = h * expf(d2);
        const float w2 = w * expf(d3);
        const float by1 = fminf(fmaxf(cy - 0.5f * h2, 0.f), HH);
        const float bx1 = fminf(fmaxf(cx - 0.5f * w2, 0.f), HH);
        const float by2 = fminf(fmaxf(cy + 0.5f * h2, 0.f), HH);
        const float bx2 = fminf(fmaxf(cx + 0.5f * w2, 0.f), HH);
        const bool valid = (cid > 0) && (score >= MIN_CONF_V);
        bx_ws[(size_t)gr * 4 + 0] = by1;
        bx_ws[(size_t)gr * 4 + 1] = bx1;
        bx_ws[(size_t)gr * 4 + 2] = by2;
        bx_ws[(size_t)gr * 4 + 3] = bx2;
        sc_ws[gr]  = valid ? score : NEGV;
        cid_ws[gr] = (float)cid;
    }
}

// ---------------- Kernel 2: per-batch stable sort + greedy NMS + emit ----------------
__global__ __launch_bounds__(1024) void k2_nms(
    const float* __restrict__ bx_ws, const float* __restrict__ sc_ws,
    const float* __restrict__ cid_ws, float* __restrict__ det)
{
    __shared__ unsigned long long keys[1024];
    __shared__ float sy1[1024], sx1[1024], sy2[1024], sx2[1024];
    __shared__ float scl[1024], ssc[1024];
    __shared__ unsigned char supp[1024];
    __shared__ int s_cnt;

    const int b = blockIdx.x;
    const int t = threadIdx.x;
    const int base = b * RR;

    unsigned long long key = 0ull;
    if (t < RR) {
        const float s = sc_ws[base + t];
        unsigned int u = __float_as_uint(s);
        u = (u & 0x80000000u) ? ~u : (u | 0x80000000u);
        key = ((unsigned long long)u << 32) | (unsigned int)(~(unsigned int)t);
    }
    keys[t] = key;
    __syncthreads();

    for (int k = 2; k <= 1024; k <<= 1) {
        for (int j = k >> 1; j > 0; j >>= 1) {
            const int ixj = t ^ j;
            if (ixj > t) {
                const unsigned long long a = keys[t];
                const unsigned long long c = keys[ixj];
                const bool desc = ((t & k) == 0);
                if (desc ? (a < c) : (a > c)) { keys[t] = c; keys[ixj] = a; }
            }
            __syncthreads();
        }
    }

    const unsigned int lo = (unsigned int)keys[t];
    const int orig = (int)(~lo);
    float sv = NEGV;
    if (orig >= 0 && orig < RR) {
        const int g = base + orig;
        sy1[t] = bx_ws[(size_t)g * 4 + 0];
        sx1[t] = bx_ws[(size_t)g * 4 + 1];
        sy2[t] = bx_ws[(size_t)g * 4 + 2];
        sx2[t] = bx_ws[(size_t)g * 4 + 3];
        scl[t] = cid_ws[g];
        sv = sc_ws[g];
    } else {
        sy1[t] = sx1[t] = sy2[t] = sx2[t] = 0.f;
        scl[t] = -1.f;
    }
    ssc[t] = sv;
    supp[t] = 0;
    if (t == 0) s_cnt = 0;
    const int V = __syncthreads_count(sv > (NEGV * 0.5f));

    for (int i = 0; i < V; ++i) {
        __syncthreads();
        if (s_cnt >= 100) break;
        if (!supp[i]) {
            if (t > i && t < V && scl[t] == scl[i]) {
                const float yy1 = fmaxf(sy1[i], sy1[t]);
                const float xx1 = fmaxf(sx1[i], sx1[t]);
                const float yy2 = fminf(sy2[i], sy2[t]);
                const float xx2 = fminf(sx2[i], sx2[t]);
                const float inter = fmaxf(yy2 - yy1, 0.f) * fmaxf(xx2 - xx1, 0.f);
                const float ai = (sy2[i] - sy1[i]) * (sx2[i] - sx1[i]);
                const float at = (sy2[t] - sy1[t]) * (sx2[t] - sx1[t]);
                const float uni = ai + at - inter;
                if (inter / fmaxf(uni, 1e-8f) > NMS_THR_V) supp[t] = 1;
            }
            if (t == 0) {
                const int slot = s_cnt;
                if (slot < 100) {
                    float* o = det + ((size_t)b * 100 + slot) * 6;
                    o[0] = sy1[i]; o[1] = sx1[i]; o[2] = sy2[i]; o[3] = sx2[i];
                    o[4] = scl[i]; o[5] = ssc[i];
                }
                s_cnt = slot + 1;
            }
        }
    }
    __syncthreads();
    int cnt = s_cnt;
    if (cnt > 100) cnt = 100;
    for (int idx = t; idx < 600; idx += 1024) {
        if (idx >= cnt * 6) det[(size_t)b * 600 + idx] = 0.f;
    }
}

extern "C" void kernel_launch(void* const* d_in, const int* in_sizes, int n_in,
                              void* d_out, int out_size, void* d_ws, size_t ws_size,
                              hipStream_t stream) {
    const float* x       = (const float*)d_in[0];
    const float* w_cls   = (const float*)d_in[1];
    const float* b_cls   = (const float*)d_in[2];
    const float* w_delta = (const float*)d_in[3];
    const float* b_delta = (const float*)d_in[4];
    const float* rois    = (const float*)d_in[5];
    float* out = (float*)d_out;

    float* bx_ws   = (float*)d_ws;               // [8000][4]
    float* sc_ws   = bx_ws + 8000 * 4;           // [8000]
    float* cid_ws  = sc_ws + 8000;               // [8000]
    float* wP      = cid_ws + 8000;              // [12][256][32] = 98304
    float* partial = wP + 98304;                 // [2][8000][96] = 1536000

    k0_wt<<<256, 128, 0, stream>>>(w_cls, w_delta, wP);
    k1_gemm<<<250, 768, 0, stream>>>(x, wP, partial);
    k1b_epi<<<125, 1024, 0, stream>>>(partial, b_cls, b_delta, rois,
                                      bx_ws, sc_ws, cid_ws);
    k2_nms<<<8, 1024, 0, stream>>>(bx_ws, sc_ws, cid_ws, out);
}